// Round 6
// baseline (167.482 us; speedup 1.0000x reference)
//
#include <hip/hip_runtime.h>

// Problem: B=64, S=128, D_MODEL=D_INNER=1024  ->  M = B*S = 8192, K = N = 1024.
// Reference simplifies: numerator/denominator == v exactly (dw>0, exp_k>0 cancel),
// so out = (sigmoid(emb@Wq+bq) * (emb@Wv+bv)) @ Wo + bo.  Wk, bk, w are dead inputs.
//
// R12: qv restructured around the two session-proven levers (schedule variants
// R7/R8/R10/R11 all pinned at ~41us -> barriers/phases/read-balance are dead):
//   - 2 blocks/CU (R9's bt lesson: cross-block TLP hides stage drain):
//     BM=128, BK=32, LDS 72KiB (3 x 24KiB slots), grid 512, 4 waves/block.
//   - 3-slot lead-2 pipeline (R8 lesson + m201's in-flight depth): tile j's
//     GLDS issued 2 iterations before use; VMCNT(6) counted; stage at top.
//   BK=32 swizzle: chunk ^= (row>>1)&3 -> worst 2-way bank alias = free (m136).
// bt, prep frozen (R9-proven: ~19us, ~12us).
// Fixed cost: harness fills 256MiB ~41us x2/rep inside timed region (~83us).

typedef short bf16x8 __attribute__((ext_vector_type(8)));  // 8 bf16 = 4 VGPRs
typedef float f32x4  __attribute__((ext_vector_type(4)));

__device__ __forceinline__ short f2bf(float f) {  // RNE fp32 -> bf16
  union { float f; unsigned u; } x; x.f = f;
  unsigned r = x.u + 0x7fffu + ((x.u >> 16) & 1u);
  return (short)(r >> 16);
}

struct alignas(16) S8 { short v[8]; };

#define GLDS(g, l) \
  __builtin_amdgcn_global_load_lds((const __attribute__((address_space(1))) void*)(g), \
                                   (__attribute__((address_space(3))) void*)(l), 16, 0, 0)
#define BAR()    __builtin_amdgcn_s_barrier()
#define PRIO(x)  __builtin_amdgcn_s_setprio(x)
#define VMCNT(N) asm volatile("s_waitcnt vmcnt(" #N ")" ::: "memory")
#define LGKM0()  asm volatile("s_waitcnt lgkmcnt(0)" ::: "memory")
#define MFMA(a, b, c) __builtin_amdgcn_mfma_f32_16x16x32_bf16((a), (b), (c), 0, 0, 0)

// ---- Phase 0: emb fp32->bf16 + transpose/cast the three 1024x1024 weights ----
__global__ __launch_bounds__(256) void prep_kernel(
    const float* __restrict__ emb, const float* __restrict__ Wq, const float* __restrict__ Wv,
    const float* __restrict__ Wo, short* __restrict__ embB, short* __restrict__ WqvT,
    short* __restrict__ WoT) {
  __shared__ float tr[64 * 65];  // pad 65 breaks column-read conflicts
  const int t = threadIdx.x;
  const int bid = blockIdx.x;
  const int gdim = gridDim.x;

  // emb cast: 1048576 groups of 8 floats -> 8 bf16
  for (size_t i = (size_t)bid * 256 + t; i < 1048576; i += (size_t)gdim * 256) {
    const float4* p = (const float4*)emb + i * 2;
    float4 a = p[0], b = p[1];
    S8 s;
    s.v[0] = f2bf(a.x); s.v[1] = f2bf(a.y); s.v[2] = f2bf(a.z); s.v[3] = f2bf(a.w);
    s.v[4] = f2bf(b.x); s.v[5] = f2bf(b.y); s.v[6] = f2bf(b.z); s.v[7] = f2bf(b.w);
    ((S8*)embB)[i] = s;
  }

  // weight transposes: 3 * 256 = 768 tiles of 64x64 (one per block at grid 768)
  const int rr = t >> 4, cc4 = (t & 15) * 4;     // read coords
  const int orow = t >> 3, ocol8 = (t & 7) * 8;  // write coords
  for (int z = bid; z < 768; z += gdim) {
    const float* in; short* op; int ti;
    if (z < 256)      { in = Wq; op = WqvT;           ti = z; }
    else if (z < 512) { in = Wv; op = WqvT + 1048576; ti = z - 256; }
    else              { in = Wo; op = WoT;            ti = z - 512; }
    const int bx = (ti & 15) * 64, by = (ti >> 4) * 64;
    __syncthreads();  // protect LDS reuse across z-iterations
#pragma unroll
    for (int k = 0; k < 4; ++k) {
      float4 v = *(const float4*)&in[(size_t)(by + rr + 16 * k) * 1024 + bx + cc4];
      float* d = &tr[(rr + 16 * k) * 65 + cc4];
      d[0] = v.x; d[1] = v.y; d[2] = v.z; d[3] = v.w;
    }
    __syncthreads();
#pragma unroll
    for (int h = 0; h < 2; ++h) {
      const int oc = orow + 32 * h;  // output row within tile = input col
      S8 s;
#pragma unroll
      for (int i = 0; i < 8; ++i) s.v[i] = f2bf(tr[(ocol8 + i) * 65 + oc]);
      *(S8*)&op[(size_t)(bx + oc) * 1024 + by + ocol8] = s;  // 16B, 128B runs
    }
  }
}

// ---- Phase 1: X = sigmoid(embB@WqT+bq) * (embB@WvT+bv), bf16. ----
// R12: BM=128, BN=128 pairs, BK=32. 256 thr (4 waves 2Mx2N, wave 64x64 q AND v).
// 3-slot pipeline, 72 KiB LDS -> 2 blocks/CU. Lead-2 staging, VMCNT(6) counted.
// grid 512 (64 bm x 8 bn), bijective XCD swizzle.
__global__ __launch_bounds__(256, 2) void gemm_qv_kernel(
    const short* __restrict__ A, const short* __restrict__ BT,  // BT=[WqT|WvT] 2048x1024
    const float* __restrict__ bq, const float* __restrict__ bv, short* __restrict__ X) {
  __shared__ short As[3][128 * 32];   // 3 x 8 KiB
  __shared__ short Bqs[3][128 * 32];  // 3 x 8 KiB
  __shared__ short Bvs[3][128 * 32];  // 3 x 8 KiB   -> 72 KiB total
  const int t = threadIdx.x;
  const int lane = t & 63;
  const int w = t >> 6;        // 0..3
  const int l16 = lane & 15;
  const int quad = lane >> 4;
  const int b = blockIdx.x;
  const int wg = (b & 7) * 64 + (b >> 3);  // bijective XCD swizzle (512%8==0)
  const int bm = (wg >> 3) * 128;          // 0..63
  const int bn = (wg & 7) * 128;           // 0..7
  const int wm = (w & 1) * 64;
  const int wn = (w >> 1) * 64;

  // staging: per K-tile 24 KiB = 6 GLDS sweeps (A rows 0-63, 64-127; Bq x2; Bv x2).
  // thread t covers row (t>>2) of the 64-row sweep, 8 bf16 at swizzled k-chunk.
  const int sr = t >> 2;                               // 0..63
  const int swk = ((t & 3) ^ ((t >> 3) & 3)) * 8;      // chunk ^ (row>>1)&3
  const short* pA0 = A + (size_t)(bm + sr) * 1024 + swk;
  const short* pA1 = pA0 + 64 * 1024;
  const short* pQ0 = BT + (size_t)(bn + sr) * 1024 + swk;
  const short* pQ1 = pQ0 + 64 * 1024;
  const short* pV0 = BT + (size_t)(1024 + bn + sr) * 1024 + swk;
  const short* pV1 = pV0 + 64 * 1024;
  short* lA = &As[0][0] + w * 512;   // wave-uniform base; HW adds lane*16B
  short* lq = &Bqs[0][0] + w * 512;
  short* lv = &Bvs[0][0] + w * 512;

#define QV_STAGE(kk, s) do {                                                  \
    GLDS(pA0 + (kk) * 32, lA + (s) * 4096);                                   \
    GLDS(pA1 + (kk) * 32, lA + (s) * 4096 + 2048);                            \
    GLDS(pQ0 + (kk) * 32, lq + (s) * 4096);                                   \
    GLDS(pQ1 + (kk) * 32, lq + (s) * 4096 + 2048);                            \
    GLDS(pV0 + (kk) * 32, lv + (s) * 4096);                                   \
    GLDS(pV1 + (kk) * 32, lv + (s) * 4096 + 2048);                            \
  } while (0)

  // fragment read addresses: row = (wm|wn) + i*16 + l16, chunk = quad ^ (l16>>1)&3
  const int csw = (quad ^ ((l16 >> 1) & 3)) * 8;
  const short* fA = &As[0][0] + (wm + l16) * 32 + csw;
  const short* fQ = &Bqs[0][0] + (wn + l16) * 32 + csw;
  const short* fV = &Bvs[0][0] + (wn + l16) * 32 + csw;

  f32x4 aq[4][4] = {};
  f32x4 av[4][4] = {};

  QV_STAGE(0, 0);
  QV_STAGE(1, 1);

  for (int j = 0; j < 32; ++j) {
    const int s = j % 3;
    // tile j landed iff at most tile j+2's 6 loads remain (in-order retirement;
    // tile j+1's 6 may also be out -> vmcnt(6) waits exactly through tile j).
    if (j < 31) { VMCNT(6); } else { VMCNT(0); }
    BAR();
    // slot (j+2)%3 was read in iter j-1 and drained at its trailing LGKM0+BAR
    // -> staging into it right after the top BAR is race-free. Lead-2: these
    // loads are needed two iterations from now.
    if (j < 30) QV_STAGE(j + 2, (j + 2) % 3);

    const short* sA = fA + s * 4096;
    const short* sQ = fQ + s * 4096;
    const short* sV = fV + s * 4096;
    bf16x8 a[4], bqf[4], bvf[4];
#pragma unroll
    for (int i = 0; i < 4; ++i) {
      a[i] = *(const bf16x8*)(sA + i * 512);
      bqf[i] = *(const bf16x8*)(sQ + i * 512);
      bvf[i] = *(const bf16x8*)(sV + i * 512);
    }
    PRIO(1);
#pragma unroll
    for (int i = 0; i < 4; ++i)
#pragma unroll
      for (int n = 0; n < 4; ++n) {
        aq[i][n] = MFMA(a[i], bqf[n], aq[i][n]);
        av[i][n] = MFMA(a[i], bvf[n], av[i][n]);
      }
    PRIO(0);
    // all of this wave's reads of slot s retired; BAR -> chip... block-wide,
    // so next iteration may stage into slot s+... = (j+3)%3 == s. Race-free.
    LGKM0();
    BAR();
  }
#undef QV_STAGE

  // epilogue: C/D layout col=lane&15, row=(lane>>4)*4+reg  [m89/m91-verified]
#pragma unroll
  for (int n = 0; n < 4; ++n) {
    const int col = bn + wn + n * 16 + l16;
    const float bql = bq[col], bvl = bv[col];
#pragma unroll
    for (int i = 0; i < 4; ++i)
#pragma unroll
      for (int r = 0; r < 4; ++r) {
        const int row = bm + wm + i * 16 + quad * 4 + r;
        const float q = aq[i][n][r] + bql;
        const float v = av[i][n][r] + bvl;
        const float sg = 1.0f / (1.0f + __expf(-q));
        X[(size_t)row * 1024 + col] = f2bf(sg * v);
      }
  }
}

// ---- Phase 2: out = X @ WoT^T + bo, fp32. R9-proven structure: 128x128 tile,
// BK=64, 256 thr (4 waves 2x2, wave 64x64), 32 KiB LDS, grid (64,8) = 512
// blocks = 2 blocks/CU. Inter-block TLP hides the staging drain. ----
__global__ __launch_bounds__(256) void gemm_bt_kernel(
    const short* __restrict__ A, const short* __restrict__ BT, float* __restrict__ C,
    const float* __restrict__ bias) {
  __shared__ short As[128 * 64];  // 16 KiB
  __shared__ short Bs[128 * 64];  // 16 KiB
  const int t = threadIdx.x;
  const int lane = t & 63;
  const int w = t >> 6;
  const int l16 = lane & 15;
  const int quad = lane >> 4;
  const int bm = blockIdx.x * 128;
  const int bn = blockIdx.y * 128;
  const int wm = (w & 1) * 64;
  const int wn = (w >> 1) * 64;

  const int r8 = t >> 3;
  const int swe = ((t & 7) ^ (r8 & 7)) * 8;
  const short* pA0 = A + (size_t)(bm + r8) * 1024 + swe;
  const short* pA1 = pA0 + 32 * 1024;
  const short* pA2 = pA0 + 64 * 1024;
  const short* pA3 = pA0 + 96 * 1024;
  const short* pB0 = BT + (size_t)(bn + r8) * 1024 + swe;
  const short* pB1 = pB0 + 32 * 1024;
  const short* pB2 = pB0 + 64 * 1024;
  const short* pB3 = pB0 + 96 * 1024;
  short* lA = As + w * 512;
  short* lB = Bs + w * 512;

  const int qsw0 = (quad ^ (l16 & 7)) * 8;
  const int qsw1 = ((quad + 4) ^ (l16 & 7)) * 8;
  const short* fA0 = As + (wm + l16) * 64 + qsw0;
  const short* fA1 = As + (wm + l16) * 64 + qsw1;
  const short* fB0 = Bs + (wn + l16) * 64 + qsw0;
  const short* fB1 = Bs + (wn + l16) * 64 + qsw1;

  f32x4 acc[4][4] = {};

  for (int it = 0; it < 16; ++it) {
    GLDS(pA0, lA); GLDS(pA1, lA + 2048); GLDS(pA2, lA + 4096); GLDS(pA3, lA + 6144);
    GLDS(pB0, lB); GLDS(pB1, lB + 2048); GLDS(pB2, lB + 4096); GLDS(pB3, lB + 6144);
    pA0 += 64; pA1 += 64; pA2 += 64; pA3 += 64;
    pB0 += 64; pB1 += 64; pB2 += 64; pB3 += 64;
    __syncthreads();

#pragma unroll
    for (int h = 0; h < 2; h++) {
      const short* fA = h ? fA1 : fA0;
      const short* fB = h ? fB1 : fB0;
      bf16x8 av[4], bw[4];
#pragma unroll
      for (int i = 0; i < 4; i++) av[i] = *(const bf16x8*)(fA + i * 1024);
#pragma unroll
      for (int j = 0; j < 4; j++) bw[j] = *(const bf16x8*)(fB + j * 1024);
#pragma unroll
      for (int i = 0; i < 4; i++)
#pragma unroll
        for (int j = 0; j < 4; j++)
          acc[i][j] = MFMA(av[i], bw[j], acc[i][j]);
    }
    __syncthreads();
  }

#pragma unroll
  for (int j = 0; j < 4; j++) {
    int col = bn + wn + j * 16 + l16;
    float bl = bias[col];
#pragma unroll
    for (int i = 0; i < 4; i++)
#pragma unroll
      for (int r = 0; r < 4; r++) {
        int row = bm + wm + i * 16 + quad * 4 + r;
        C[(size_t)row * 1024 + col] = acc[i][j][r] + bl;
      }
  }
}

extern "C" void kernel_launch(void* const* d_in, const int* in_sizes, int n_in,
                              void* d_out, int out_size, void* d_ws, size_t ws_size,
                              hipStream_t stream) {
  const float* emb = (const float*)d_in[0];
  const float* Wq  = (const float*)d_in[1];
  const float* bq  = (const float*)d_in[2];
  // d_in[3]=Wk, d_in[4]=bk, d_in[7]=w are mathematically dead (they cancel)
  const float* Wv  = (const float*)d_in[5];
  const float* bv  = (const float*)d_in[6];
  const float* Wo  = (const float*)d_in[8];
  const float* bo  = (const float*)d_in[9];
  float* out = (float*)d_out;

  // workspace layout (bytes)
  char* ws = (char*)d_ws;
  short* embB = (short*)(ws);                 // 8192*1024 bf16 = 16 MiB
  short* X    = (short*)(ws + 16777216);      // 8192*1024 bf16 = 16 MiB
  short* WqvT = (short*)(ws + 33554432);      // [WqT | WvT] 2048*1024 = 4 MiB
  short* WoT  = (short*)(ws + 37748736);      // 1024*1024 = 2 MiB
  // total: 39,845,888 bytes

  prep_kernel<<<768, 256, 0, stream>>>(emb, Wq, Wv, Wo, embB, WqvT, WoT);
  gemm_qv_kernel<<<512, 256, 0, stream>>>(embB, WqvT, bq, bv, X);
  gemm_bt_kernel<<<dim3(64, 8), 256, 0, stream>>>(X, WoT, out, bo);
}